// Round 8
// baseline (2180.223 us; speedup 1.0000x reference)
//
#include <hip/hip_runtime.h>

#define BATCH   32768
#define DIM     256
#define NCODES  8192
#define BETA    0.25f
#define EPS     3e-4f     // screen window: grid-tie ulp + 2*delta(bf16 screen) + bf16-tilemin fuzz
#define CAND_CAP 128      // per-row LDS candidate slots (avg ~16; overflow handled inline)

typedef unsigned short ushort_t;
typedef unsigned char  uchar_t;
typedef unsigned long long u64;
typedef __attribute__((ext_vector_type(8))) short bf16x8;
typedef __attribute__((ext_vector_type(4))) float f32x4;

__device__ inline ushort_t f2bf(float f) {  // RNE float->bf16 (no NaN in data)
    union { float f; unsigned u; } v; v.f = f;
    return (ushort_t)((v.u + 0x7FFF + ((v.u >> 16) & 1)) >> 16);
}
__device__ inline ushort_t f2bf_rd(float f) {  // round toward -inf (conservative tilemin)
    union { float f; unsigned u; } v; v.f = f;
    unsigned u = v.u;
    if (f < 0.0f) u += 0xFFFFu;   // magnitude up for negatives => value down
    return (ushort_t)(u >> 16);
}

// ============================================================================
// Kernel A: fused prep. One wave per row (codebook rows then z rows):
// e2[k]/z2[b] row sums-of-squares + bf16 copies eh/zh. Zeroes the loss
// accumulator (d_ws is poisoned 0xAA every launch).
// ============================================================================
__global__ void vq_prep_kernel(const float* __restrict__ z,
                               const float* __restrict__ cb,
                               float* __restrict__ e2, float* __restrict__ z2,
                               ushort_t* __restrict__ eh, ushort_t* __restrict__ zh,
                               float* __restrict__ loss_acc) {
    const int lane = threadIdx.x & 63;
    const int wid  = threadIdx.x >> 6;
    const int item = blockIdx.x * 4 + wid;
    const float* src;
    ushort_t* dst;
    if (item < NCODES) { src = cb + (size_t)item * DIM;            dst = eh + (size_t)item * DIM; }
    else               { src = z  + (size_t)(item - NCODES) * DIM; dst = zh + (size_t)(item - NCODES) * DIM; }
    const float4 v = *(const float4*)(src + lane * 4);
    ushort4 b; b.x = f2bf(v.x); b.y = f2bf(v.y); b.z = f2bf(v.z); b.w = f2bf(v.w);
    *(ushort4*)(dst + lane * 4) = b;
    float s = v.x * v.x + v.y * v.y + v.z * v.z + v.w * v.w;
    #pragma unroll
    for (int off = 32; off > 0; off >>= 1) s += __shfl_down(s, off, 64);
    if (lane == 0) {
        if (item < NCODES) e2[item] = s;
        else               z2[item - NCODES] = s;
    }
    if (blockIdx.x == 0 && threadIdx.x == 0) *loss_acc = 0.0f;
}

// ============================================================================
// Kernel B: MFMA screen -- R16: NO LDS, NO BARRIERS, ALL-VGPR fragments.
// The R8-R15 invariant (chunk period ~5000 cyc at 20-23% MfmaUtil across
// drain/counted-vmcnt/16-wave/8-phase/2-block/m97-geometry variants, and
// R15's decisive "fewer staged bytes -> SLOWER") pins the wall on the
// global_load_lds DMA path itself + its per-chunk drain -- unfixable from
// inside a barrier-locked block. So the staging is eliminated entirely:
//   - BM=128 x BN=128 per block, 4 waves (256 thr), acc[2][8] = 64 AGPR
//     (R14-proven 60 arch VGPR with this inner loop).
//   - A (zh) AND B (eh) fragments load global->VGPR directly. Per-lane
//     address (tile-row lane&15, k8 (lane>>4)*8) reproduces the staged LDS
//     image exactly (R14-verified for A) -> bit-identical MFMA inputs.
//   - B is shared by the 4 waves: 4x duplicated reads served by L1 (8 KB
//     chunk-slice; R14 precedent) or worst-case L2.
//   - no __syncthreads anywhere: waves fully independent; compiler's own
//     vmcnt scheduling overlaps chunk n+1 loads with chunk n MFMAs; ~8
//     blocks/CU (launch_bounds(256,8), 0 LDS) provide TLP.
//   - L2 locality by construction: bn partitioned per XCD (XCD x owns bn
//     x*8..x*8+7 -> its 8 eh panels = 512 KB stay L2-resident; eh never
//     duplicated across XCDs), bn-minor ordering (8 consecutive blocks
//     share one zh panel while hot). zh (16 MB) + eh (4 MB) are L3-resident.
// Outputs bit-identical to R5-R15: same kc-ascending accumulation chain
// per acc[i][j], same fragment mapping, same mask/tilemin encoding.
// ============================================================================
__launch_bounds__(256, 8)
__global__ void vq_screen_kernel(const ushort_t* __restrict__ zh_g,
                                 const ushort_t* __restrict__ eh_g,
                                 const float* __restrict__ e2g,
                                 ushort_t* __restrict__ tilemin_g,
                                 uchar_t* __restrict__ mask_g) {
    const int t    = threadIdx.x;
    const int w    = t >> 6;        // wave 0..3: rows w*32..w*32+31
    const int lane = t & 63;
    const int c    = lane & 15;     // MFMA col / fragment row
    const int q    = lane >> 4;     // MFMA quad
    const unsigned bid = blockIdx.x;
    // bn partitioned per XCD; bn-minor within XCD (8 blocks share a zh panel)
    const int xcd = (int)(bid & 7u);
    const int u   = (int)(bid >> 3);        // 0..2047
    const int bm  = u >> 3;                 // 0..255
    const int bn  = xcd * 8 + (u & 7);      // 0..63, fixed range per XCD
    const int row0 = bm * 128;
    const int srow = lane & 15;
    const int skc  = (lane >> 4) * 8;

    const ushort_t* zp0 = zh_g + (size_t)(row0 + w * 32 + srow) * DIM + skc;
    const ushort_t* zp1 = zp0 + (size_t)16 * DIM;
    const ushort_t* ep  = eh_g + (size_t)(bn * 128 + srow) * DIM + skc;

    // chunk n (kc = n*32) fragment loads, direct global->VGPR
    #define LDA(n_, a0_, a1_) do {                                             \
        a0_ = *(const bf16x8*)(zp0 + (n_) * 32);                               \
        a1_ = *(const bf16x8*)(zp1 + (n_) * 32);                               \
    } while (0)
    #define LDB(n_, bb_) do {                                                  \
        _Pragma("unroll")                                                      \
        for (int j_ = 0; j_ < 8; ++j_)                                         \
            bb_[j_] = *(const bf16x8*)(ep + (size_t)(j_ * 16) * DIM + (n_) * 32); \
    } while (0)

    bf16x8 a0, a1, an0, an1, bcur[8], bnxt[8];
    LDA(0, a0, a1);
    LDB(0, bcur);

    f32x4 acc[2][8];
    #pragma unroll
    for (int i = 0; i < 2; ++i)
        #pragma unroll
        for (int j = 0; j < 8; ++j) acc[i][j] = (f32x4)0.0f;

    #pragma unroll
    for (int n = 0; n < 8; ++n) {
        if (n < 7) { LDA(n + 1, an0, an1); LDB(n + 1, bnxt); }
        #pragma unroll
        for (int j = 0; j < 8; ++j) {
            acc[0][j] = __builtin_amdgcn_mfma_f32_16x16x32_bf16(a0, bcur[j], acc[0][j], 0, 0, 0);
            acc[1][j] = __builtin_amdgcn_mfma_f32_16x16x32_bf16(a1, bcur[j], acc[1][j], 0, 0, 0);
        }
        a0 = an0; a1 = an1;            // static rotation (loop fully unrolled)
        #pragma unroll
        for (int j = 0; j < 8; ++j) bcur[j] = bnxt[j];
    }

    // epilogue, once per block: scores, per-row tile min, mask bits.
    float e2v[8];
    #pragma unroll
    for (int j = 0; j < 8; ++j) e2v[j] = e2g[bn * 128 + j * 16 + c];

    float tm[2][4];
    #pragma unroll
    for (int i = 0; i < 2; ++i)
        #pragma unroll
        for (int reg = 0; reg < 4; ++reg) tm[i][reg] = 3.4e38f;
    #pragma unroll
    for (int i = 0; i < 2; ++i)
        #pragma unroll
        for (int j = 0; j < 8; ++j)
            #pragma unroll
            for (int reg = 0; reg < 4; ++reg) {
                const float s = fmaf(-2.0f, acc[i][j][reg], e2v[j]);
                acc[i][j][reg] = s;
                tm[i][reg] = fminf(tm[i][reg], s);
            }
    #pragma unroll
    for (int st = 1; st < 16; st <<= 1)
        #pragma unroll
        for (int i = 0; i < 2; ++i)
            #pragma unroll
            for (int reg = 0; reg < 4; ++reg)
                tm[i][reg] = fminf(tm[i][reg], __shfl_xor(tm[i][reg], st, 64));

    const int tile = bn;
    #pragma unroll
    for (int i = 0; i < 2; ++i)
        #pragma unroll
        for (int reg = 0; reg < 4; ++reg) {
            const int row = row0 + w * 32 + i * 16 + q * 4 + reg;
            const float thr = tm[i][reg] + EPS;
            unsigned m8 = 0;
            #pragma unroll
            for (int j = 0; j < 8; ++j)
                m8 |= (unsigned)(acc[i][j][reg] <= thr) << j;
            mask_g[(size_t)row * 1024 + tile * 16 + c] = (uchar_t)m8;
            if (c == 0) tilemin_g[(size_t)row * 64 + tile] = f2bf_rd(tm[i][reg]);
        }
    #undef LDA
    #undef LDB
}

// ============================================================================
// exact score, bit-identical to R2's verified numerics: ascending-k
// sequential fmaf; S = fl(z2+e2); score = fl(S - 2*acc). Returns
// (score_bits<<32 | code): positive scores => float bits monotone; u64 min
// over candidates => lowest code on exact grid ties.
// ============================================================================
__device__ inline u64 vq_eval(const float* zrow, const float* __restrict__ cb,
                              const float* __restrict__ e2g, float z2v, int code) {
    const float4* z4 = (const float4*)zrow;
    const float4* e4 = (const float4*)(cb + (size_t)code * DIM);
    float acc = 0.0f;
    #pragma unroll 8
    for (int k4 = 0; k4 < DIM / 4; ++k4) {
        const float4 a = z4[k4];
        const float4 b = e4[k4];
        acc = fmaf(a.x, b.x, acc);
        acc = fmaf(a.y, b.y, acc);
        acc = fmaf(a.z, b.z, acc);
        acc = fmaf(a.w, b.w, acc);
    }
    const float S  = z2v + e2g[code];
    const float sc = fmaf(-2.0f, acc, S);
    union { float f; unsigned u; } sb; sb.f = sc;
    return ((u64)sb.u << 32) | (unsigned)code;
}

// ============================================================================
// Kernel C: fused select + gather + loss (R15-verified).
// ONE WAVE PER ROW (lane = tile): coalesced bf16 tile-min load, butterfly
// gmin, active lanes enumerate their tile's mask into per-wave LDS slots
// via prefix scan; lane = slot evaluates exact scores (z row LDS-cached);
// in-wave u64 butterfly min -> ALL lanes hold the winner; then gather
// zq_st = fl(z + fl(cb[k] - z)) + the same 4-row-block loss partial and
// one atomicAdd per block. ALIASING: mask_g shares d_out's zq region
// row-for-row; each block reads only its own 4 rows' masks (to registers,
// before barrier #1) and writes only its own 4 rows' zq at the end.
// ============================================================================
__global__ void vq_select_kernel(const float* __restrict__ z,
                                 const float* __restrict__ cb,
                                 const float* __restrict__ e2g,
                                 const float* __restrict__ z2g,
                                 const ushort_t* __restrict__ tilemin_g,
                                 const uchar_t* __restrict__ mask_g,
                                 float* __restrict__ idx_f,
                                 float* __restrict__ zq_out,
                                 float* __restrict__ loss_acc) {
    __shared__ float    zrow_s[4][DIM];
    __shared__ ushort_t cand_s[4][CAND_CAP];
    __shared__ float    wsum[4];

    const int lane = threadIdx.x & 63;
    const int w    = threadIdx.x >> 6;
    const int row  = blockIdx.x * 4 + w;

    // stage z row (float4/lane); visible to other lanes after barrier #1
    *(float4*)&zrow_s[w][lane * 4] = *(const float4*)(z + (size_t)row * DIM + lane * 4);

    union { unsigned u; float f; } tv;
    tv.u = ((unsigned)tilemin_g[(size_t)row * 64 + lane]) << 16;
    const float tm = tv.f;
    float gmin = tm;
    #pragma unroll
    for (int d = 32; d > 0; d >>= 1) gmin = fminf(gmin, __shfl_xor(gmin, d, 64));
    const float thr = gmin + EPS;

    u64 m0 = 0, m1 = 0;
    if (tm <= thr) {
        const uchar_t* mb = mask_g + (size_t)row * 1024 + lane * 16;
        m0 = *(const u64*)(mb);
        m1 = *(const u64*)(mb + 8);
    }
    const unsigned cnt = __popcll(m0) + __popcll(m1);
    unsigned inc = cnt;
    #pragma unroll
    for (int d = 1; d < 64; d <<= 1) {
        const unsigned o = __shfl_up(inc, d, 64);
        if (lane >= d) inc += o;
    }
    const unsigned excl  = inc - cnt;
    const unsigned total = __shfl(inc, 63, 64);
    const float z2v = z2g[row];
    u64 best = ~0ull;

    __syncthreads();   // barrier #1: zrow_s visible (overflow eval below reads it)

    // emit candidates (bit p in m0/m1: byte c = p>>3, bit j = p&7 -> code j*16+c)
    unsigned slot = excl;
    while (m0) {
        const int p = __builtin_ctzll(m0); m0 &= m0 - 1;
        const unsigned code = lane * 128 + (p & 7) * 16 + (p >> 3);
        if (slot < CAND_CAP) cand_s[w][slot] = (ushort_t)code;
        else best = min(best, vq_eval(zrow_s[w], cb, e2g, z2v, (int)code));
        ++slot;
    }
    while (m1) {
        const int p = __builtin_ctzll(m1); m1 &= m1 - 1;
        const unsigned code = lane * 128 + (p & 7) * 16 + 8 + (p >> 3);
        if (slot < CAND_CAP) cand_s[w][slot] = (ushort_t)code;
        else best = min(best, vq_eval(zrow_s[w], cb, e2g, z2v, (int)code));
        ++slot;
    }

    __syncthreads();   // barrier #2: cand_s visible

    const int n = (int)(total < CAND_CAP ? total : CAND_CAP);
    for (int s = lane; s < n; s += 64)
        best = min(best, vq_eval(zrow_s[w], cb, e2g, z2v, (int)cand_s[w][s]));

    #pragma unroll
    for (int d = 32; d > 0; d >>= 1) {
        const u64 o = (u64)__shfl_xor((unsigned long long)best, d, 64);
        best = min(best, o);
    }
    // all lanes hold the winner after the butterfly
    const int k = (int)(best & (u64)(NCODES - 1));
    if (lane == 0) idx_f[row] = (float)k;

    // ---- fused gather + ST + loss (bit-identical arithmetic) ----
    const float4 e  = *(const float4*)(cb + (size_t)k * DIM + lane * 4);
    const float4 zv = *(const float4*)&zrow_s[w][lane * 4];
    const float dx = e.x - zv.x, dy = e.y - zv.y, dz = e.z - zv.z, dw = e.w - zv.w;
    float4 o;
    o.x = zv.x + dx; o.y = zv.y + dy; o.z = zv.z + dz; o.w = zv.w + dw;
    *(float4*)(zq_out + (size_t)row * DIM + lane * 4) = o;   // overwrites this row's mask (done with it)
    float s = dx * dx + dy * dy + dz * dz + dw * dw;
    #pragma unroll
    for (int off = 32; off > 0; off >>= 1) s += __shfl_down(s, off, 64);
    if (lane == 0) wsum[w] = s;
    __syncthreads();
    if (threadIdx.x == 0)
        atomicAdd(loss_acc, wsum[0] + wsum[1] + wsum[2] + wsum[3]);
}

// ============================================================================
// Kernel E: finalize scalars.
// ============================================================================
__global__ void vq_finalize_kernel(const float* __restrict__ loss_acc,
                                   float* __restrict__ out_losses) {
    const float mean = *loss_acc * (1.0f / (float)(BATCH * DIM));  // /2^23 exact
    out_losses[0] = mean + BETA * mean;    // vq_loss
    out_losses[1] = mean;                  // cb_loss
    out_losses[2] = mean;                  // commit_loss
}

// ============================================================================
extern "C" void kernel_launch(void* const* d_in, const int* in_sizes, int n_in,
                              void* d_out, int out_size, void* d_ws, size_t ws_size,
                              hipStream_t stream) {
    const float* z  = (const float*)d_in[0];   // [32768, 256] fp32
    const float* cb = (const float*)d_in[1];   // [8192, 256]  fp32

    float* out    = (float*)d_out;
    float* zq     = out;                                   // [32768*256]
    float* idx_f  = out + (size_t)BATCH * DIM;             // [32768]
    float* losses = out + (size_t)BATCH * DIM + BATCH;     // [3]
    uchar_t* mask = (uchar_t*)d_out;                       // zq region reused: 1 KB/row

    // ws layout (~20.5 MB): ctrl[256 f] | e2 | z2 | tilemin(u16) | zh(u16) | eh(u16)
    float*    ws        = (float*)d_ws;
    float*    loss_acc  = ws;                                       // [0]
    float*    e2        = ws + 256;                                 // 8192 f
    float*    z2        = e2 + NCODES;                              // 32768 f
    ushort_t* tilemin   = (ushort_t*)(z2 + BATCH);                  // 32768*64 u16
    ushort_t* zh        = tilemin + (size_t)BATCH * 64;             // 32768*256 u16
    ushort_t* eh        = zh + (size_t)BATCH * DIM;                 // 8192*256 u16

    vq_prep_kernel<<<(NCODES + BATCH) / 4, 256, 0, stream>>>(z, cb, e2, z2, eh, zh, loss_acc);
    vq_screen_kernel<<<(BATCH / 128) * (NCODES / 128), 256, 0, stream>>>(zh, eh, e2, tilemin, mask);
    vq_select_kernel<<<BATCH / 4, 256, 0, stream>>>(z, cb, e2, z2, tilemin, mask, idx_f, zq, loss_acc);
    vq_finalize_kernel<<<1, 1, 0, stream>>>(loss_acc, losses);
}

// Round 9
// 803.411 us; speedup vs baseline: 2.7137x; 2.7137x over previous
//
#include <hip/hip_runtime.h>

#define BATCH   32768
#define DIM     256
#define NCODES  8192
#define BETA    0.25f
#define EPS     3e-4f     // screen window: grid-tie ulp + 2*delta(bf16 screen) + bf16-tilemin fuzz
#define CAND_CAP 128      // per-row LDS candidate slots (avg ~16; overflow handled inline)

typedef unsigned short ushort_t;
typedef unsigned char  uchar_t;
typedef unsigned long long u64;
typedef __attribute__((ext_vector_type(8))) short bf16x8;
typedef __attribute__((ext_vector_type(4))) float f32x4;

__device__ inline ushort_t f2bf(float f) {  // RNE float->bf16 (no NaN in data)
    union { float f; unsigned u; } v; v.f = f;
    return (ushort_t)((v.u + 0x7FFF + ((v.u >> 16) & 1)) >> 16);
}
__device__ inline ushort_t f2bf_rd(float f) {  // round toward -inf (conservative tilemin)
    union { float f; unsigned u; } v; v.f = f;
    unsigned u = v.u;
    if (f < 0.0f) u += 0xFFFFu;   // magnitude up for negatives => value down
    return (ushort_t)(u >> 16);
}

// ============================================================================
// Kernel A: fused prep. One wave per row (codebook rows then z rows):
// e2[k]/z2[b] row sums-of-squares + bf16 copies eh/zh. Zeroes the loss
// accumulator (d_ws is poisoned 0xAA every launch).
// ============================================================================
__global__ void vq_prep_kernel(const float* __restrict__ z,
                               const float* __restrict__ cb,
                               float* __restrict__ e2, float* __restrict__ z2,
                               ushort_t* __restrict__ eh, ushort_t* __restrict__ zh,
                               float* __restrict__ loss_acc) {
    const int lane = threadIdx.x & 63;
    const int wid  = threadIdx.x >> 6;
    const int item = blockIdx.x * 4 + wid;
    const float* src;
    ushort_t* dst;
    if (item < NCODES) { src = cb + (size_t)item * DIM;            dst = eh + (size_t)item * DIM; }
    else               { src = z  + (size_t)(item - NCODES) * DIM; dst = zh + (size_t)(item - NCODES) * DIM; }
    const float4 v = *(const float4*)(src + lane * 4);
    ushort4 b; b.x = f2bf(v.x); b.y = f2bf(v.y); b.z = f2bf(v.z); b.w = f2bf(v.w);
    *(ushort4*)(dst + lane * 4) = b;
    float s = v.x * v.x + v.y * v.y + v.z * v.z + v.w * v.w;
    #pragma unroll
    for (int off = 32; off > 0; off >>= 1) s += __shfl_down(s, off, 64);
    if (lane == 0) {
        if (item < NCODES) e2[item] = s;
        else               z2[item - NCODES] = s;
    }
    if (blockIdx.x == 0 && threadIdx.x == 0) *loss_acc = 0.0f;
}

// ============================================================================
// Kernel B: MFMA screen -- R17: no-LDS/no-barrier structure (R16), register
// budget FIXED. R16's launch_bounds(256,8) capped each wave at 512/8 = 64
// unified regs = the accumulator alone -> total spill (WRITE 6.1 GB scratch,
// MfmaUtil 2.8%). This round budgets for 3 waves/SIMD (m97's proven
// residency): launch_bounds(256,3) -> ~170 regs/wave. Pressure discipline:
// the 8 B-fragments are processed in two HALF-PHASES of 4 (load 4, MFMA 8,
// load next 4, MFMA 8) so live regs stay ~140: acc 64 + A cur/next 16 +
// B halves 2x16 + temps. The j-split does NOT touch the per-acc[i][j]
// kc-ascending MFMA chain -> outputs bit-identical to R5-R16.
// Structure recap: BM=128 x BN=128 per block, 4 waves; A and B fragments
// load global->VGPR directly (per-lane addr (srow=lane&15, skc=(lane>>4)*8)
// = the staged-LDS image, R14/R16-verified); no __syncthreads anywhere;
// 3 independent blocks/CU; bn partitioned per XCD (8 eh panels = 512 KB
// L2-hot per XCD, zero cross-XCD eh duplication), bn-minor ordering so 8
// consecutive blocks reuse one zh panel. L1 absorbs the 4x intra-block B
// duplication (8 KB chunk-slice/CU).
// ============================================================================
__launch_bounds__(256, 3)
__global__ void vq_screen_kernel(const ushort_t* __restrict__ zh_g,
                                 const ushort_t* __restrict__ eh_g,
                                 const float* __restrict__ e2g,
                                 ushort_t* __restrict__ tilemin_g,
                                 uchar_t* __restrict__ mask_g) {
    const int t    = threadIdx.x;
    const int w    = t >> 6;        // wave 0..3: rows w*32..w*32+31
    const int lane = t & 63;
    const int c    = lane & 15;     // MFMA col / fragment row
    const int q    = lane >> 4;     // MFMA quad
    const unsigned bid = blockIdx.x;
    // bn partitioned per XCD; bn-minor within XCD (8 blocks share a zh panel)
    const int xcd = (int)(bid & 7u);
    const int u   = (int)(bid >> 3);        // 0..2047
    const int bm  = u >> 3;                 // 0..255
    const int bn  = xcd * 8 + (u & 7);      // 0..63, fixed range per XCD
    const int row0 = bm * 128;
    const int srow = lane & 15;
    const int skc  = (lane >> 4) * 8;

    const ushort_t* zp0 = zh_g + (size_t)(row0 + w * 32 + srow) * DIM + skc;
    const ushort_t* zp1 = zp0 + (size_t)16 * DIM;
    const ushort_t* ep  = eh_g + (size_t)(bn * 128 + srow) * DIM + skc;

    // chunk n (kc = n*32): A fragments and a HALF (4) of the B fragments
    #define LDA(n_, a0_, a1_) do {                                             \
        a0_ = *(const bf16x8*)(zp0 + (n_) * 32);                               \
        a1_ = *(const bf16x8*)(zp1 + (n_) * 32);                               \
    } while (0)
    #define LDBH(n_, h_, bb_) do {                                             \
        _Pragma("unroll")                                                      \
        for (int j_ = 0; j_ < 4; ++j_)                                         \
            bb_[j_] = *(const bf16x8*)(ep + (size_t)(((h_) * 4 + j_) * 16) * DIM + (n_) * 32); \
    } while (0)

    bf16x8 a0, a1, an0, an1, bh0[4], bh1[4];
    LDA(0, a0, a1);
    LDBH(0, 0, bh0);

    f32x4 acc[2][8];
    #pragma unroll
    for (int i = 0; i < 2; ++i)
        #pragma unroll
        for (int j = 0; j < 8; ++j) acc[i][j] = (f32x4)0.0f;

    #pragma unroll
    for (int n = 0; n < 8; ++n) {
        // phase 0: prefetch this chunk's upper B half, MFMA lower half
        LDBH(n, 1, bh1);
        #pragma unroll
        for (int j = 0; j < 4; ++j) {
            acc[0][j] = __builtin_amdgcn_mfma_f32_16x16x32_bf16(a0, bh0[j], acc[0][j], 0, 0, 0);
            acc[1][j] = __builtin_amdgcn_mfma_f32_16x16x32_bf16(a1, bh0[j], acc[1][j], 0, 0, 0);
        }
        // phase 1: prefetch next chunk's A + lower B half, MFMA upper half
        if (n < 7) { LDA(n + 1, an0, an1); LDBH(n + 1, 0, bh0); }
        #pragma unroll
        for (int j = 0; j < 4; ++j) {
            acc[0][j + 4] = __builtin_amdgcn_mfma_f32_16x16x32_bf16(a0, bh1[j], acc[0][j + 4], 0, 0, 0);
            acc[1][j + 4] = __builtin_amdgcn_mfma_f32_16x16x32_bf16(a1, bh1[j], acc[1][j + 4], 0, 0, 0);
        }
        a0 = an0; a1 = an1;            // static rotation (loop fully unrolled)
    }

    // epilogue, once per block: scores, per-row tile min, mask bits.
    float e2v[8];
    #pragma unroll
    for (int j = 0; j < 8; ++j) e2v[j] = e2g[bn * 128 + j * 16 + c];

    float tm[2][4];
    #pragma unroll
    for (int i = 0; i < 2; ++i)
        #pragma unroll
        for (int reg = 0; reg < 4; ++reg) tm[i][reg] = 3.4e38f;
    #pragma unroll
    for (int i = 0; i < 2; ++i)
        #pragma unroll
        for (int j = 0; j < 8; ++j)
            #pragma unroll
            for (int reg = 0; reg < 4; ++reg) {
                const float s = fmaf(-2.0f, acc[i][j][reg], e2v[j]);
                acc[i][j][reg] = s;
                tm[i][reg] = fminf(tm[i][reg], s);
            }
    #pragma unroll
    for (int st = 1; st < 16; st <<= 1)
        #pragma unroll
        for (int i = 0; i < 2; ++i)
            #pragma unroll
            for (int reg = 0; reg < 4; ++reg)
                tm[i][reg] = fminf(tm[i][reg], __shfl_xor(tm[i][reg], st, 64));

    const int tile = bn;
    #pragma unroll
    for (int i = 0; i < 2; ++i)
        #pragma unroll
        for (int reg = 0; reg < 4; ++reg) {
            const int row = row0 + w * 32 + i * 16 + q * 4 + reg;
            const float thr = tm[i][reg] + EPS;
            unsigned m8 = 0;
            #pragma unroll
            for (int j = 0; j < 8; ++j)
                m8 |= (unsigned)(acc[i][j][reg] <= thr) << j;
            mask_g[(size_t)row * 1024 + tile * 16 + c] = (uchar_t)m8;
            if (c == 0) tilemin_g[(size_t)row * 64 + tile] = f2bf_rd(tm[i][reg]);
        }
    #undef LDA
    #undef LDBH
}

// ============================================================================
// exact score, bit-identical to R2's verified numerics: ascending-k
// sequential fmaf; S = fl(z2+e2); score = fl(S - 2*acc). Returns
// (score_bits<<32 | code): positive scores => float bits monotone; u64 min
// over candidates => lowest code on exact grid ties.
// ============================================================================
__device__ inline u64 vq_eval(const float* zrow, const float* __restrict__ cb,
                              const float* __restrict__ e2g, float z2v, int code) {
    const float4* z4 = (const float4*)zrow;
    const float4* e4 = (const float4*)(cb + (size_t)code * DIM);
    float acc = 0.0f;
    #pragma unroll 8
    for (int k4 = 0; k4 < DIM / 4; ++k4) {
        const float4 a = z4[k4];
        const float4 b = e4[k4];
        acc = fmaf(a.x, b.x, acc);
        acc = fmaf(a.y, b.y, acc);
        acc = fmaf(a.z, b.z, acc);
        acc = fmaf(a.w, b.w, acc);
    }
    const float S  = z2v + e2g[code];
    const float sc = fmaf(-2.0f, acc, S);
    union { float f; unsigned u; } sb; sb.f = sc;
    return ((u64)sb.u << 32) | (unsigned)code;
}

// ============================================================================
// Kernel C: fused select + gather + loss (R15-verified).
// ONE WAVE PER ROW (lane = tile): coalesced bf16 tile-min load, butterfly
// gmin, active lanes enumerate their tile's mask into per-wave LDS slots
// via prefix scan; lane = slot evaluates exact scores (z row LDS-cached);
// in-wave u64 butterfly min -> ALL lanes hold the winner; then gather
// zq_st = fl(z + fl(cb[k] - z)) + the same 4-row-block loss partial and
// one atomicAdd per block. ALIASING: mask_g shares d_out's zq region
// row-for-row; each block reads only its own 4 rows' masks (to registers,
// before barrier #1) and writes only its own 4 rows' zq at the end.
// ============================================================================
__global__ void vq_select_kernel(const float* __restrict__ z,
                                 const float* __restrict__ cb,
                                 const float* __restrict__ e2g,
                                 const float* __restrict__ z2g,
                                 const ushort_t* __restrict__ tilemin_g,
                                 const uchar_t* __restrict__ mask_g,
                                 float* __restrict__ idx_f,
                                 float* __restrict__ zq_out,
                                 float* __restrict__ loss_acc) {
    __shared__ float    zrow_s[4][DIM];
    __shared__ ushort_t cand_s[4][CAND_CAP];
    __shared__ float    wsum[4];

    const int lane = threadIdx.x & 63;
    const int w    = threadIdx.x >> 6;
    const int row  = blockIdx.x * 4 + w;

    // stage z row (float4/lane); visible to other lanes after barrier #1
    *(float4*)&zrow_s[w][lane * 4] = *(const float4*)(z + (size_t)row * DIM + lane * 4);

    union { unsigned u; float f; } tv;
    tv.u = ((unsigned)tilemin_g[(size_t)row * 64 + lane]) << 16;
    const float tm = tv.f;
    float gmin = tm;
    #pragma unroll
    for (int d = 32; d > 0; d >>= 1) gmin = fminf(gmin, __shfl_xor(gmin, d, 64));
    const float thr = gmin + EPS;

    u64 m0 = 0, m1 = 0;
    if (tm <= thr) {
        const uchar_t* mb = mask_g + (size_t)row * 1024 + lane * 16;
        m0 = *(const u64*)(mb);
        m1 = *(const u64*)(mb + 8);
    }
    const unsigned cnt = __popcll(m0) + __popcll(m1);
    unsigned inc = cnt;
    #pragma unroll
    for (int d = 1; d < 64; d <<= 1) {
        const unsigned o = __shfl_up(inc, d, 64);
        if (lane >= d) inc += o;
    }
    const unsigned excl  = inc - cnt;
    const unsigned total = __shfl(inc, 63, 64);
    const float z2v = z2g[row];
    u64 best = ~0ull;

    __syncthreads();   // barrier #1: zrow_s visible (overflow eval below reads it)

    // emit candidates (bit p in m0/m1: byte c = p>>3, bit j = p&7 -> code j*16+c)
    unsigned slot = excl;
    while (m0) {
        const int p = __builtin_ctzll(m0); m0 &= m0 - 1;
        const unsigned code = lane * 128 + (p & 7) * 16 + (p >> 3);
        if (slot < CAND_CAP) cand_s[w][slot] = (ushort_t)code;
        else best = min(best, vq_eval(zrow_s[w], cb, e2g, z2v, (int)code));
        ++slot;
    }
    while (m1) {
        const int p = __builtin_ctzll(m1); m1 &= m1 - 1;
        const unsigned code = lane * 128 + (p & 7) * 16 + 8 + (p >> 3);
        if (slot < CAND_CAP) cand_s[w][slot] = (ushort_t)code;
        else best = min(best, vq_eval(zrow_s[w], cb, e2g, z2v, (int)code));
        ++slot;
    }

    __syncthreads();   // barrier #2: cand_s visible

    const int n = (int)(total < CAND_CAP ? total : CAND_CAP);
    for (int s = lane; s < n; s += 64)
        best = min(best, vq_eval(zrow_s[w], cb, e2g, z2v, (int)cand_s[w][s]));

    #pragma unroll
    for (int d = 32; d > 0; d >>= 1) {
        const u64 o = (u64)__shfl_xor((unsigned long long)best, d, 64);
        best = min(best, o);
    }
    // all lanes hold the winner after the butterfly
    const int k = (int)(best & (u64)(NCODES - 1));
    if (lane == 0) idx_f[row] = (float)k;

    // ---- fused gather + ST + loss (bit-identical arithmetic) ----
    const float4 e  = *(const float4*)(cb + (size_t)k * DIM + lane * 4);
    const float4 zv = *(const float4*)&zrow_s[w][lane * 4];
    const float dx = e.x - zv.x, dy = e.y - zv.y, dz = e.z - zv.z, dw = e.w - zv.w;
    float4 o;
    o.x = zv.x + dx; o.y = zv.y + dy; o.z = zv.z + dz; o.w = zv.w + dw;
    *(float4*)(zq_out + (size_t)row * DIM + lane * 4) = o;   // overwrites this row's mask (done with it)
    float s = dx * dx + dy * dy + dz * dz + dw * dw;
    #pragma unroll
    for (int off = 32; off > 0; off >>= 1) s += __shfl_down(s, off, 64);
    if (lane == 0) wsum[w] = s;
    __syncthreads();
    if (threadIdx.x == 0)
        atomicAdd(loss_acc, wsum[0] + wsum[1] + wsum[2] + wsum[3]);
}

// ============================================================================
// Kernel E: finalize scalars.
// ============================================================================
__global__ void vq_finalize_kernel(const float* __restrict__ loss_acc,
                                   float* __restrict__ out_losses) {
    const float mean = *loss_acc * (1.0f / (float)(BATCH * DIM));  // /2^23 exact
    out_losses[0] = mean + BETA * mean;    // vq_loss
    out_losses[1] = mean;                  // cb_loss
    out_losses[2] = mean;                  // commit_loss
}

// ============================================================================
extern "C" void kernel_launch(void* const* d_in, const int* in_sizes, int n_in,
                              void* d_out, int out_size, void* d_ws, size_t ws_size,
                              hipStream_t stream) {
    const float* z  = (const float*)d_in[0];   // [32768, 256] fp32
    const float* cb = (const float*)d_in[1];   // [8192, 256]  fp32

    float* out    = (float*)d_out;
    float* zq     = out;                                   // [32768*256]
    float* idx_f  = out + (size_t)BATCH * DIM;             // [32768]
    float* losses = out + (size_t)BATCH * DIM + BATCH;     // [3]
    uchar_t* mask = (uchar_t*)d_out;                       // zq region reused: 1 KB/row

    // ws layout (~20.5 MB): ctrl[256 f] | e2 | z2 | tilemin(u16) | zh(u16) | eh(u16)
    float*    ws        = (float*)d_ws;
    float*    loss_acc  = ws;                                       // [0]
    float*    e2        = ws + 256;                                 // 8192 f
    float*    z2        = e2 + NCODES;                              // 32768 f
    ushort_t* tilemin   = (ushort_t*)(z2 + BATCH);                  // 32768*64 u16
    ushort_t* zh        = tilemin + (size_t)BATCH * 64;             // 32768*256 u16
    ushort_t* eh        = zh + (size_t)BATCH * DIM;                 // 8192*256 u16

    vq_prep_kernel<<<(NCODES + BATCH) / 4, 256, 0, stream>>>(z, cb, e2, z2, eh, zh, loss_acc);
    vq_screen_kernel<<<(BATCH / 128) * (NCODES / 128), 256, 0, stream>>>(zh, eh, e2, tilemin, mask);
    vq_select_kernel<<<BATCH / 4, 256, 0, stream>>>(z, cb, e2, z2, tilemin, mask, idx_f, zq, loss_acc);
    vq_finalize_kernel<<<1, 1, 0, stream>>>(loss_acc, losses);
}

// Round 10
// 482.742 us; speedup vs baseline: 4.5163x; 1.6643x over previous
//
#include <hip/hip_runtime.h>

#define BATCH   32768
#define DIM     256
#define NCODES  8192
#define BETA    0.25f
#define EPS     3e-4f     // screen window: grid-tie ulp + 2*delta(bf16 screen) + bf16-tilemin fuzz
#define CAND_CAP 128      // per-row LDS candidate slots (avg ~16; overflow handled inline)

typedef unsigned short ushort_t;
typedef unsigned char  uchar_t;
typedef unsigned long long u64;
typedef __attribute__((ext_vector_type(8))) short bf16x8;
typedef __attribute__((ext_vector_type(4))) float f32x4;

// async global->LDS, 16B per lane; dest = wave-uniform base + lane*16
#define GLOAD16(gp, lp) __builtin_amdgcn_global_load_lds( \
    (const __attribute__((address_space(1))) void*)(gp), \
    (__attribute__((address_space(3))) void*)(lp), 16, 0, 0)

__device__ inline ushort_t f2bf(float f) {  // RNE float->bf16 (no NaN in data)
    union { float f; unsigned u; } v; v.f = f;
    return (ushort_t)((v.u + 0x7FFF + ((v.u >> 16) & 1)) >> 16);
}
__device__ inline ushort_t f2bf_rd(float f) {  // round toward -inf (conservative tilemin)
    union { float f; unsigned u; } v; v.f = f;
    unsigned u = v.u;
    if (f < 0.0f) u += 0xFFFFu;   // magnitude up for negatives => value down
    return (ushort_t)(u >> 16);
}

// ============================================================================
// Kernel A: fused prep. One wave per row (codebook rows then z rows):
// e2[k]/z2[b] row sums-of-squares + bf16 copies eh/zh. Zeroes the loss
// accumulator (d_ws is poisoned 0xAA every launch).
// ============================================================================
__global__ void vq_prep_kernel(const float* __restrict__ z,
                               const float* __restrict__ cb,
                               float* __restrict__ e2, float* __restrict__ z2,
                               ushort_t* __restrict__ eh, ushort_t* __restrict__ zh,
                               float* __restrict__ loss_acc) {
    const int lane = threadIdx.x & 63;
    const int wid  = threadIdx.x >> 6;
    const int item = blockIdx.x * 4 + wid;
    const float* src;
    ushort_t* dst;
    if (item < NCODES) { src = cb + (size_t)item * DIM;            dst = eh + (size_t)item * DIM; }
    else               { src = z  + (size_t)(item - NCODES) * DIM; dst = zh + (size_t)(item - NCODES) * DIM; }
    const float4 v = *(const float4*)(src + lane * 4);
    ushort4 b; b.x = f2bf(v.x); b.y = f2bf(v.y); b.z = f2bf(v.z); b.w = f2bf(v.w);
    *(ushort4*)(dst + lane * 4) = b;
    float s = v.x * v.x + v.y * v.y + v.z * v.z + v.w * v.w;
    #pragma unroll
    for (int off = 32; off > 0; off >>= 1) s += __shfl_down(s, off, 64);
    if (lane == 0) {
        if (item < NCODES) e2[item] = s;
        else               z2[item - NCODES] = s;
    }
    if (blockIdx.x == 0 && threadIdx.x == 0) *loss_acc = 0.0f;
}

// ============================================================================
// Kernel B: MFMA screen, 128 ROWS/BLOCK, 8 waves (512 thr) -- R18: BK=64.
// R17 closed the structure search: direct-VGPR fragments are latency-bound
// (8.8% MfmaUtil); LDS staging (R8, 255us, 22.6%) is the best base. The
// remaining untested lever on R8 is the CHUNK COUNT: R8's period decomposes
// as 4780 cyc = bytes/rate + FIXED overhead (issue+DMA latency+drain+barrier
// reconvergence), and R15 proved the fixed term dominates (32 KB chunks ran
// SLOWER, 5250, than 40 KB, 4780 -> period is not byte-proportional). So:
// half the chunks at double the size. BK=64 (two 32-K substeps per chunk):
//   - 64 chunks x 80 KB; LDS dbuf = 2x(16 KB zh + 64 KB eh) = 160 KB
//     EXACTLY (full pool; AITER attn runs 160 KB blocks on gfx950).
//   - per chunk per wave: 10 gloads, then per-substep {read frags, 32
//     MFMA} so live operand regs stay at R8's level (128 arch + 128 acc).
//   - T2 pre-swizzled staging (R11/R15-verified bit-identical, 0 LDS
//     conflicts): lane fetches (tile-row lane&15, k8 lane>>4); linear dest
//     = reader layout; reader lane l reads base + l*16B.
//   - accumulation chain: ct fixed, kc_i 0..3, ks 0..1 -> k ascending
//     0,32,...,224 per acc[i][j] -- IDENTICAL to R8's chain -> outputs
//     bit-identical. Epilogue every 4th chunk (ct = n>>2), same encoding.
// Wave w: row-half h=w>>2 (64 rows), code-quarter cq=w&3 (128 codes).
// ============================================================================
__launch_bounds__(512, 2)
__global__ void vq_screen_kernel(const ushort_t* __restrict__ zh_g,
                                 const ushort_t* __restrict__ eh_g,
                                 const float* __restrict__ e2g,
                                 ushort_t* __restrict__ tilemin_g,
                                 uchar_t* __restrict__ mask_g) {
    __shared__ ushort_t zh_s[2][16 * 512];   // dbuf: [ks][row-tile 0..7] (16 KB/buf)
    __shared__ ushort_t eh_s[2][64 * 512];   // dbuf: [ks][code-tile 0..31] (64 KB/buf)

    const int t    = threadIdx.x;
    const int w    = t >> 6;        // wave 0..7
    const int lane = t & 63;
    const int c    = lane & 15;     // MFMA col / fragment row
    const int q    = lane >> 4;     // MFMA quad
    const int h    = w >> 2;        // row half (0: rows 0-63, 1: 64-127)
    const int cq   = w & 3;         // code quarter within the 512-code group
    const int row0 = blockIdx.x * 128;
    // T2 pre-swizzled stage source (R11/R15-verified)
    const int srow = lane & 15;
    const int skc  = (lane >> 4) * 8;

    // stage chunk n (ct = n>>2, kc = (n&3)*64; two 32-K substeps) into buf b:
    // wave w stages zh row-tile w (x2 ksub) + eh tiles w*4..w*4+3 (x2 ksub)
    #define STAGE(n_, b_) do {                                                 \
        const int ct_ = (n_) >> 2;                                             \
        const int kc_ = ((n_) & 3) * 64;                                       \
        _Pragma("unroll")                                                      \
        for (int ks_ = 0; ks_ < 2; ++ks_) {                                    \
            GLOAD16(zh_g + (size_t)(row0 + w * 16 + srow) * DIM + kc_ + ks_ * 32 + skc, \
                    &zh_s[b_][(ks_ * 8 + w) * 512]);                           \
            _Pragma("unroll")                                                  \
            for (int s_ = 0; s_ < 4; ++s_) {                                   \
                const int c16_ = w * 4 + s_;                                   \
                GLOAD16(eh_g + (size_t)(ct_ * 512 + c16_ * 16 + srow) * DIM + kc_ + ks_ * 32 + skc, \
                        &eh_s[b_][(ks_ * 32 + c16_) * 512]);                   \
            }                                                                  \
        }                                                                      \
    } while (0)

    STAGE(0, 0);

    f32x4 acc[4][8];
    for (int n = 0; n < 64; ++n) {
        const int kc_i = n & 3;
        if (kc_i == 0) {            // register-only; overlaps in-flight DMA
            #pragma unroll
            for (int i = 0; i < 4; ++i)
                #pragma unroll
                for (int j = 0; j < 8; ++j) acc[i][j] = (f32x4)0.0f;
        }
        __syncthreads();               // drains GLOADs (chunk n DMA complete)
        if (n < 63) STAGE(n + 1, (n + 1) & 1);
        const int b = n & 1;

        #pragma unroll
        for (int ks = 0; ks < 2; ++ks) {
            bf16x8 a[4], bfr[8];
            #pragma unroll
            for (int i = 0; i < 4; ++i)
                a[i] = *(const bf16x8*)&zh_s[b][(ks * 8 + h * 4 + i) * 512 + lane * 8];
            #pragma unroll
            for (int j = 0; j < 8; ++j)
                bfr[j] = *(const bf16x8*)&eh_s[b][(ks * 32 + cq * 8 + j) * 512 + lane * 8];
            #pragma unroll
            for (int i = 0; i < 4; ++i)
                #pragma unroll
                for (int j = 0; j < 8; ++j)
                    acc[i][j] = __builtin_amdgcn_mfma_f32_16x16x32_bf16(a[i], bfr[j], acc[i][j], 0, 0, 0);
        }

        if (kc_i == 3) {
            // epilogue for ct group: scores, per-row tile min, mask bits.
            const int ct = n >> 2;
            float e2v[8];
            #pragma unroll
            for (int j = 0; j < 8; ++j) e2v[j] = e2g[ct * 512 + cq * 128 + j * 16 + c];

            float tm[4][4];
            #pragma unroll
            for (int i = 0; i < 4; ++i)
                #pragma unroll
                for (int reg = 0; reg < 4; ++reg) tm[i][reg] = 3.4e38f;
            #pragma unroll
            for (int i = 0; i < 4; ++i)
                #pragma unroll
                for (int j = 0; j < 8; ++j)
                    #pragma unroll
                    for (int reg = 0; reg < 4; ++reg) {
                        const float s = fmaf(-2.0f, acc[i][j][reg], e2v[j]);
                        acc[i][j][reg] = s;
                        tm[i][reg] = fminf(tm[i][reg], s);
                    }
            #pragma unroll
            for (int st = 1; st < 16; st <<= 1)
                #pragma unroll
                for (int i = 0; i < 4; ++i)
                    #pragma unroll
                    for (int reg = 0; reg < 4; ++reg)
                        tm[i][reg] = fminf(tm[i][reg], __shfl_xor(tm[i][reg], st, 64));

            const int tile = ct * 4 + cq;
            #pragma unroll
            for (int i = 0; i < 4; ++i)
                #pragma unroll
                for (int reg = 0; reg < 4; ++reg) {
                    const int row = row0 + h * 64 + i * 16 + q * 4 + reg;
                    const float thr = tm[i][reg] + EPS;
                    unsigned m8 = 0;
                    #pragma unroll
                    for (int j = 0; j < 8; ++j)
                        m8 |= (unsigned)(acc[i][j][reg] <= thr) << j;
                    mask_g[(size_t)row * 1024 + tile * 16 + c] = (uchar_t)m8;
                    if (c == 0) tilemin_g[(size_t)row * 64 + tile] = f2bf_rd(tm[i][reg]);
                }
        }
    }
    #undef STAGE
}

// ============================================================================
// exact score, bit-identical to R2's verified numerics: ascending-k
// sequential fmaf; S = fl(z2+e2); score = fl(S - 2*acc). Returns
// (score_bits<<32 | code): positive scores => float bits monotone; u64 min
// over candidates => lowest code on exact grid ties.
// ============================================================================
__device__ inline u64 vq_eval(const float* zrow, const float* __restrict__ cb,
                              const float* __restrict__ e2g, float z2v, int code) {
    const float4* z4 = (const float4*)zrow;
    const float4* e4 = (const float4*)(cb + (size_t)code * DIM);
    float acc = 0.0f;
    #pragma unroll 8
    for (int k4 = 0; k4 < DIM / 4; ++k4) {
        const float4 a = z4[k4];
        const float4 b = e4[k4];
        acc = fmaf(a.x, b.x, acc);
        acc = fmaf(a.y, b.y, acc);
        acc = fmaf(a.z, b.z, acc);
        acc = fmaf(a.w, b.w, acc);
    }
    const float S  = z2v + e2g[code];
    const float sc = fmaf(-2.0f, acc, S);
    union { float f; unsigned u; } sb; sb.f = sc;
    return ((u64)sb.u << 32) | (unsigned)code;
}

// ============================================================================
// Kernel C: fused select + gather + loss (R15-verified).
// ONE WAVE PER ROW (lane = tile): coalesced bf16 tile-min load, butterfly
// gmin, active lanes enumerate their tile's mask into per-wave LDS slots
// via prefix scan; lane = slot evaluates exact scores (z row LDS-cached);
// in-wave u64 butterfly min -> ALL lanes hold the winner; then gather
// zq_st = fl(z + fl(cb[k] - z)) + the same 4-row-block loss partial and
// one atomicAdd per block. ALIASING: mask_g shares d_out's zq region
// row-for-row; each block reads only its own 4 rows' masks (to registers,
// before barrier #1) and writes only its own 4 rows' zq at the end.
// ============================================================================
__global__ void vq_select_kernel(const float* __restrict__ z,
                                 const float* __restrict__ cb,
                                 const float* __restrict__ e2g,
                                 const float* __restrict__ z2g,
                                 const ushort_t* __restrict__ tilemin_g,
                                 const uchar_t* __restrict__ mask_g,
                                 float* __restrict__ idx_f,
                                 float* __restrict__ zq_out,
                                 float* __restrict__ loss_acc) {
    __shared__ float    zrow_s[4][DIM];
    __shared__ ushort_t cand_s[4][CAND_CAP];
    __shared__ float    wsum[4];

    const int lane = threadIdx.x & 63;
    const int w    = threadIdx.x >> 6;
    const int row  = blockIdx.x * 4 + w;

    // stage z row (float4/lane); visible to other lanes after barrier #1
    *(float4*)&zrow_s[w][lane * 4] = *(const float4*)(z + (size_t)row * DIM + lane * 4);

    union { unsigned u; float f; } tv;
    tv.u = ((unsigned)tilemin_g[(size_t)row * 64 + lane]) << 16;
    const float tm = tv.f;
    float gmin = tm;
    #pragma unroll
    for (int d = 32; d > 0; d >>= 1) gmin = fminf(gmin, __shfl_xor(gmin, d, 64));
    const float thr = gmin + EPS;

    u64 m0 = 0, m1 = 0;
    if (tm <= thr) {
        const uchar_t* mb = mask_g + (size_t)row * 1024 + lane * 16;
        m0 = *(const u64*)(mb);
        m1 = *(const u64*)(mb + 8);
    }
    const unsigned cnt = __popcll(m0) + __popcll(m1);
    unsigned inc = cnt;
    #pragma unroll
    for (int d = 1; d < 64; d <<= 1) {
        const unsigned o = __shfl_up(inc, d, 64);
        if (lane >= d) inc += o;
    }
    const unsigned excl  = inc - cnt;
    const unsigned total = __shfl(inc, 63, 64);
    const float z2v = z2g[row];
    u64 best = ~0ull;

    __syncthreads();   // barrier #1: zrow_s visible (overflow eval below reads it)

    // emit candidates (bit p in m0/m1: byte c = p>>3, bit j = p&7 -> code j*16+c)
    unsigned slot = excl;
    while (m0) {
        const int p = __builtin_ctzll(m0); m0 &= m0 - 1;
        const unsigned code = lane * 128 + (p & 7) * 16 + (p >> 3);
        if (slot < CAND_CAP) cand_s[w][slot] = (ushort_t)code;
        else best = min(best, vq_eval(zrow_s[w], cb, e2g, z2v, (int)code));
        ++slot;
    }
    while (m1) {
        const int p = __builtin_ctzll(m1); m1 &= m1 - 1;
        const unsigned code = lane * 128 + (p & 7) * 16 + 8 + (p >> 3);
        if (slot < CAND_CAP) cand_s[w][slot] = (ushort_t)code;
        else best = min(best, vq_eval(zrow_s[w], cb, e2g, z2v, (int)code));
        ++slot;
    }

    __syncthreads();   // barrier #2: cand_s visible

    const int n = (int)(total < CAND_CAP ? total : CAND_CAP);
    for (int s = lane; s < n; s += 64)
        best = min(best, vq_eval(zrow_s[w], cb, e2g, z2v, (int)cand_s[w][s]));

    #pragma unroll
    for (int d = 32; d > 0; d >>= 1) {
        const u64 o = (u64)__shfl_xor((unsigned long long)best, d, 64);
        best = min(best, o);
    }
    // all lanes hold the winner after the butterfly
    const int k = (int)(best & (u64)(NCODES - 1));
    if (lane == 0) idx_f[row] = (float)k;

    // ---- fused gather + ST + loss (bit-identical arithmetic) ----
    const float4 e  = *(const float4*)(cb + (size_t)k * DIM + lane * 4);
    const float4 zv = *(const float4*)&zrow_s[w][lane * 4];
    const float dx = e.x - zv.x, dy = e.y - zv.y, dz = e.z - zv.z, dw = e.w - zv.w;
    float4 o;
    o.x = zv.x + dx; o.y = zv.y + dy; o.z = zv.z + dz; o.w = zv.w + dw;
    *(float4*)(zq_out + (size_t)row * DIM + lane * 4) = o;   // overwrites this row's mask (done with it)
    float s = dx * dx + dy * dy + dz * dz + dw * dw;
    #pragma unroll
    for (int off = 32; off > 0; off >>= 1) s += __shfl_down(s, off, 64);
    if (lane == 0) wsum[w] = s;
    __syncthreads();
    if (threadIdx.x == 0)
        atomicAdd(loss_acc, wsum[0] + wsum[1] + wsum[2] + wsum[3]);
}

// ============================================================================
// Kernel E: finalize scalars.
// ============================================================================
__global__ void vq_finalize_kernel(const float* __restrict__ loss_acc,
                                   float* __restrict__ out_losses) {
    const float mean = *loss_acc * (1.0f / (float)(BATCH * DIM));  // /2^23 exact
    out_losses[0] = mean + BETA * mean;    // vq_loss
    out_losses[1] = mean;                  // cb_loss
    out_losses[2] = mean;                  // commit_loss
}

// ============================================================================
extern "C" void kernel_launch(void* const* d_in, const int* in_sizes, int n_in,
                              void* d_out, int out_size, void* d_ws, size_t ws_size,
                              hipStream_t stream) {
    const float* z  = (const float*)d_in[0];   // [32768, 256] fp32
    const float* cb = (const float*)d_in[1];   // [8192, 256]  fp32

    float* out    = (float*)d_out;
    float* zq     = out;                                   // [32768*256]
    float* idx_f  = out + (size_t)BATCH * DIM;             // [32768]
    float* losses = out + (size_t)BATCH * DIM + BATCH;     // [3]
    uchar_t* mask = (uchar_t*)d_out;                       // zq region reused: 1 KB/row

    // ws layout (~20.5 MB): ctrl[256 f] | e2 | z2 | tilemin(u16) | zh(u16) | eh(u16)
    float*    ws        = (float*)d_ws;
    float*    loss_acc  = ws;                                       // [0]
    float*    e2        = ws + 256;                                 // 8192 f
    float*    z2        = e2 + NCODES;                              // 32768 f
    ushort_t* tilemin   = (ushort_t*)(z2 + BATCH);                  // 32768*64 u16
    ushort_t* zh        = tilemin + (size_t)BATCH * 64;             // 32768*256 u16
    ushort_t* eh        = zh + (size_t)BATCH * DIM;                 // 8192*256 u16

    vq_prep_kernel<<<(NCODES + BATCH) / 4, 256, 0, stream>>>(z, cb, e2, z2, eh, zh, loss_acc);
    vq_screen_kernel<<<BATCH / 128, 512, 0, stream>>>(zh, eh, e2, tilemin, mask);
    vq_select_kernel<<<BATCH / 4, 256, 0, stream>>>(z, cb, e2, z2, tilemin, mask, idx_f, zq, loss_acc);
    vq_finalize_kernel<<<1, 1, 0, stream>>>(loss_acc, losses);
}

// Round 11
// 467.577 us; speedup vs baseline: 4.6628x; 1.0324x over previous
//
#include <hip/hip_runtime.h>

#define BATCH   32768
#define DIM     256
#define NCODES  8192
#define BETA    0.25f
#define EPS     3e-4f     // screen window: grid-tie ulp + 2*delta(bf16 screen) + bf16-tilemin fuzz
#define CAND_CAP 128      // per-row LDS candidate slots (avg ~16; overflow handled inline)

typedef unsigned short ushort_t;
typedef unsigned char  uchar_t;
typedef unsigned long long u64;
typedef __attribute__((ext_vector_type(8))) short bf16x8;
typedef __attribute__((ext_vector_type(4))) float f32x4;

// async global->LDS, 16B per lane; dest = wave-uniform base + lane*16
#define GLOAD16(gp, lp) __builtin_amdgcn_global_load_lds( \
    (const __attribute__((address_space(1))) void*)(gp), \
    (__attribute__((address_space(3))) void*)(lp), 16, 0, 0)

__device__ inline ushort_t f2bf(float f) {  // RNE float->bf16 (no NaN in data)
    union { float f; unsigned u; } v; v.f = f;
    return (ushort_t)((v.u + 0x7FFF + ((v.u >> 16) & 1)) >> 16);
}
__device__ inline ushort_t f2bf_rd(float f) {  // round toward -inf (conservative tilemin)
    union { float f; unsigned u; } v; v.f = f;
    unsigned u = v.u;
    if (f < 0.0f) u += 0xFFFFu;   // magnitude up for negatives => value down
    return (ushort_t)(u >> 16);
}

// ============================================================================
// Kernel A: fused prep. One wave per row (codebook rows then z rows):
// e2[k]/z2[b] row sums-of-squares + bf16 copies eh/zh. Zeroes the loss
// accumulator (d_ws is poisoned 0xAA every launch).
// ============================================================================
__global__ void vq_prep_kernel(const float* __restrict__ z,
                               const float* __restrict__ cb,
                               float* __restrict__ e2, float* __restrict__ z2,
                               ushort_t* __restrict__ eh, ushort_t* __restrict__ zh,
                               float* __restrict__ loss_acc) {
    const int lane = threadIdx.x & 63;
    const int wid  = threadIdx.x >> 6;
    const int item = blockIdx.x * 4 + wid;
    const float* src;
    ushort_t* dst;
    if (item < NCODES) { src = cb + (size_t)item * DIM;            dst = eh + (size_t)item * DIM; }
    else               { src = z  + (size_t)(item - NCODES) * DIM; dst = zh + (size_t)(item - NCODES) * DIM; }
    const float4 v = *(const float4*)(src + lane * 4);
    ushort4 b; b.x = f2bf(v.x); b.y = f2bf(v.y); b.z = f2bf(v.z); b.w = f2bf(v.w);
    *(ushort4*)(dst + lane * 4) = b;
    float s = v.x * v.x + v.y * v.y + v.z * v.z + v.w * v.w;
    #pragma unroll
    for (int off = 32; off > 0; off >>= 1) s += __shfl_down(s, off, 64);
    if (lane == 0) {
        if (item < NCODES) e2[item] = s;
        else               z2[item - NCODES] = s;
    }
    if (blockIdx.x == 0 && threadIdx.x == 0) *loss_acc = 0.0f;
}

// ============================================================================
// Kernel B: MFMA screen -- R19: R14's verified kernel, SWIZZLE FIXED.
// R14 re-audit: per-block chunk period ~4100 cyc (the same 4-5K invariant
// seen in R8/R15/R18), but with 3 co-resident blocks the CU should
// interleave to ~68% MfmaUtil. It measured 20% because R14 was HBM-bound
// BY MY SWIZZLE: partitioning bn per XCD forces every XCD to stream the
// whole 16 MB zh (8x duplication = FETCH 229 MB at 930 GB/s, latency-bound,
// no interleave). Fix: partition BM per XCD (each XCD owns 32 contiguous
// zh panels = 2 MB, streamed once), bn-minor inner (the shared 4 MB eh
// cycles through each XCD's L2; L2-resident after the first bm pass;
// L3-resident globally). Ideal HBM fetch ~20 MB.
// Geometry (R14, verified passing): BM=128 x BN=128, 4 waves (256 thr),
// acc[2][8] = 64 AGPR + 60 arch VGPR, launch_bounds(256,3) -> 3 blocks/CU,
// LDS 16 KB dbuf (eh only); A-fragments direct global->VGPR (bit-identical
// to staged image); eh staged via T2 pre-swizzled gload_lds (0 conflicts);
// epilogue once per block. Outputs bit-identical to R5-R18.
// ============================================================================
__launch_bounds__(256, 3)
__global__ void vq_screen_kernel(const ushort_t* __restrict__ zh_g,
                                 const ushort_t* __restrict__ eh_g,
                                 const float* __restrict__ e2g,
                                 ushort_t* __restrict__ tilemin_g,
                                 uchar_t* __restrict__ mask_g) {
    __shared__ ushort_t eh_s[2][8 * 512];   // dbuf: 8 code-subtiles of [16][32]

    const int t    = threadIdx.x;
    const int w    = t >> 6;        // wave 0..3: rows w*32..w*32+31
    const int lane = t & 63;
    const int c    = lane & 15;     // MFMA col / fragment row
    const int q    = lane >> 4;     // MFMA quad
    const unsigned bid = blockIdx.x;
    // FIXED swizzle: bm partitioned per XCD (zh 2 MB/XCD, streamed once);
    // bn-minor within XCD (eh 4 MB cycles -> L2-resident after first pass).
    const int xcd = (int)(bid & 7u);
    const int u   = (int)(bid >> 3);        // 0..2047
    const int bm  = xcd * 32 + (u >> 6);    // XCD x owns bm in [x*32, x*32+32)
    const int bn  = u & 63;                 // 0..63, inner loop
    const int row0 = bm * 128;
    const int srow = lane & 15;
    const int skc  = (lane >> 4) * 8;

    // stage eh chunk n (kc = n*32) into buffer b: wave w stages subtiles 2w, 2w+1
    #define STAGE(n_, b_) do {                                                  \
        _Pragma("unroll")                                                       \
        for (int s_ = 0; s_ < 2; ++s_) {                                        \
            const int c16_ = w * 2 + s_;                                        \
            GLOAD16(eh_g + (size_t)(bn * 128 + c16_ * 16 + srow) * DIM + (n_) * 32 + skc, \
                    &eh_s[b_][c16_ * 512]);                                     \
        }                                                                       \
    } while (0)
    // direct A-fragment loads (global->VGPR, bypass LDS); same per-lane data
    // as the staged path, double-buffered across chunks.
    #define LOADA(n_, d0_, d1_) do {                                            \
        d0_ = *(const bf16x8*)(zh_g + (size_t)(row0 + w * 32 + srow) * DIM + (n_) * 32 + skc);      \
        d1_ = *(const bf16x8*)(zh_g + (size_t)(row0 + w * 32 + 16 + srow) * DIM + (n_) * 32 + skc); \
    } while (0)

    bf16x8 a0, a1, an0, an1;
    STAGE(0, 0);
    LOADA(0, a0, a1);

    f32x4 acc[2][8];
    #pragma unroll
    for (int i = 0; i < 2; ++i)
        #pragma unroll
        for (int j = 0; j < 8; ++j) acc[i][j] = (f32x4)0.0f;

    #pragma unroll
    for (int n = 0; n < 8; ++n) {
        __syncthreads();               // chunk n staged (barrier drains vmem)
        if (n < 7) { STAGE(n + 1, (n + 1) & 1); LOADA(n + 1, an0, an1); }

        bf16x8 bfr[8];
        #pragma unroll
        for (int j = 0; j < 8; ++j)
            bfr[j] = *(const bf16x8*)&eh_s[n & 1][j * 512 + lane * 8];
        #pragma unroll
        for (int j = 0; j < 8; ++j) {
            acc[0][j] = __builtin_amdgcn_mfma_f32_16x16x32_bf16(a0, bfr[j], acc[0][j], 0, 0, 0);
            acc[1][j] = __builtin_amdgcn_mfma_f32_16x16x32_bf16(a1, bfr[j], acc[1][j], 0, 0, 0);
        }
        a0 = an0; a1 = an1;            // static (loop fully unrolled)
    }

    // epilogue, once per block: scores, per-row tile min, mask bits.
    float e2v[8];
    #pragma unroll
    for (int j = 0; j < 8; ++j) e2v[j] = e2g[bn * 128 + j * 16 + c];

    float tm[2][4];
    #pragma unroll
    for (int i = 0; i < 2; ++i)
        #pragma unroll
        for (int reg = 0; reg < 4; ++reg) tm[i][reg] = 3.4e38f;
    #pragma unroll
    for (int i = 0; i < 2; ++i)
        #pragma unroll
        for (int j = 0; j < 8; ++j)
            #pragma unroll
            for (int reg = 0; reg < 4; ++reg) {
                const float s = fmaf(-2.0f, acc[i][j][reg], e2v[j]);
                acc[i][j][reg] = s;
                tm[i][reg] = fminf(tm[i][reg], s);
            }
    #pragma unroll
    for (int st = 1; st < 16; st <<= 1)
        #pragma unroll
        for (int i = 0; i < 2; ++i)
            #pragma unroll
            for (int reg = 0; reg < 4; ++reg)
                tm[i][reg] = fminf(tm[i][reg], __shfl_xor(tm[i][reg], st, 64));

    const int tile = bn;
    #pragma unroll
    for (int i = 0; i < 2; ++i)
        #pragma unroll
        for (int reg = 0; reg < 4; ++reg) {
            const int row = row0 + w * 32 + i * 16 + q * 4 + reg;
            const float thr = tm[i][reg] + EPS;
            unsigned m8 = 0;
            #pragma unroll
            for (int j = 0; j < 8; ++j)
                m8 |= (unsigned)(acc[i][j][reg] <= thr) << j;
            mask_g[(size_t)row * 1024 + tile * 16 + c] = (uchar_t)m8;
            if (c == 0) tilemin_g[(size_t)row * 64 + tile] = f2bf_rd(tm[i][reg]);
        }
    #undef STAGE
    #undef LOADA
}

// ============================================================================
// exact score, bit-identical to R2's verified numerics: ascending-k
// sequential fmaf; S = fl(z2+e2); score = fl(S - 2*acc). Returns
// (score_bits<<32 | code): positive scores => float bits monotone; u64 min
// over candidates => lowest code on exact grid ties.
// ============================================================================
__device__ inline u64 vq_eval(const float* zrow, const float* __restrict__ cb,
                              const float* __restrict__ e2g, float z2v, int code) {
    const float4* z4 = (const float4*)zrow;
    const float4* e4 = (const float4*)(cb + (size_t)code * DIM);
    float acc = 0.0f;
    #pragma unroll 8
    for (int k4 = 0; k4 < DIM / 4; ++k4) {
        const float4 a = z4[k4];
        const float4 b = e4[k4];
        acc = fmaf(a.x, b.x, acc);
        acc = fmaf(a.y, b.y, acc);
        acc = fmaf(a.z, b.z, acc);
        acc = fmaf(a.w, b.w, acc);
    }
    const float S  = z2v + e2g[code];
    const float sc = fmaf(-2.0f, acc, S);
    union { float f; unsigned u; } sb; sb.f = sc;
    return ((u64)sb.u << 32) | (unsigned)code;
}

// ============================================================================
// Kernel C: fused select + gather + loss (R15-verified).
// ONE WAVE PER ROW (lane = tile): coalesced bf16 tile-min load, butterfly
// gmin, active lanes enumerate their tile's mask into per-wave LDS slots
// via prefix scan; lane = slot evaluates exact scores (z row LDS-cached);
// in-wave u64 butterfly min -> ALL lanes hold the winner; then gather
// zq_st = fl(z + fl(cb[k] - z)) + the same 4-row-block loss partial and
// one atomicAdd per block. ALIASING: mask_g shares d_out's zq region
// row-for-row; each block reads only its own 4 rows' masks (to registers,
// before barrier #1) and writes only its own 4 rows' zq at the end.
// ============================================================================
__global__ void vq_select_kernel(const float* __restrict__ z,
                                 const float* __restrict__ cb,
                                 const float* __restrict__ e2g,
                                 const float* __restrict__ z2g,
                                 const ushort_t* __restrict__ tilemin_g,
                                 const uchar_t* __restrict__ mask_g,
                                 float* __restrict__ idx_f,
                                 float* __restrict__ zq_out,
                                 float* __restrict__ loss_acc) {
    __shared__ float    zrow_s[4][DIM];
    __shared__ ushort_t cand_s[4][CAND_CAP];
    __shared__ float    wsum[4];

    const int lane = threadIdx.x & 63;
    const int w    = threadIdx.x >> 6;
    const int row  = blockIdx.x * 4 + w;

    // stage z row (float4/lane); visible to other lanes after barrier #1
    *(float4*)&zrow_s[w][lane * 4] = *(const float4*)(z + (size_t)row * DIM + lane * 4);

    union { unsigned u; float f; } tv;
    tv.u = ((unsigned)tilemin_g[(size_t)row * 64 + lane]) << 16;
    const float tm = tv.f;
    float gmin = tm;
    #pragma unroll
    for (int d = 32; d > 0; d >>= 1) gmin = fminf(gmin, __shfl_xor(gmin, d, 64));
    const float thr = gmin + EPS;

    u64 m0 = 0, m1 = 0;
    if (tm <= thr) {
        const uchar_t* mb = mask_g + (size_t)row * 1024 + lane * 16;
        m0 = *(const u64*)(mb);
        m1 = *(const u64*)(mb + 8);
    }
    const unsigned cnt = __popcll(m0) + __popcll(m1);
    unsigned inc = cnt;
    #pragma unroll
    for (int d = 1; d < 64; d <<= 1) {
        const unsigned o = __shfl_up(inc, d, 64);
        if (lane >= d) inc += o;
    }
    const unsigned excl  = inc - cnt;
    const unsigned total = __shfl(inc, 63, 64);
    const float z2v = z2g[row];
    u64 best = ~0ull;

    __syncthreads();   // barrier #1: zrow_s visible (overflow eval below reads it)

    // emit candidates (bit p in m0/m1: byte c = p>>3, bit j = p&7 -> code j*16+c)
    unsigned slot = excl;
    while (m0) {
        const int p = __builtin_ctzll(m0); m0 &= m0 - 1;
        const unsigned code = lane * 128 + (p & 7) * 16 + (p >> 3);
        if (slot < CAND_CAP) cand_s[w][slot] = (ushort_t)code;
        else best = min(best, vq_eval(zrow_s[w], cb, e2g, z2v, (int)code));
        ++slot;
    }
    while (m1) {
        const int p = __builtin_ctzll(m1); m1 &= m1 - 1;
        const unsigned code = lane * 128 + (p & 7) * 16 + 8 + (p >> 3);
        if (slot < CAND_CAP) cand_s[w][slot] = (ushort_t)code;
        else best = min(best, vq_eval(zrow_s[w], cb, e2g, z2v, (int)code));
        ++slot;
    }

    __syncthreads();   // barrier #2: cand_s visible

    const int n = (int)(total < CAND_CAP ? total : CAND_CAP);
    for (int s = lane; s < n; s += 64)
        best = min(best, vq_eval(zrow_s[w], cb, e2g, z2v, (int)cand_s[w][s]));

    #pragma unroll
    for (int d = 32; d > 0; d >>= 1) {
        const u64 o = (u64)__shfl_xor((unsigned long long)best, d, 64);
        best = min(best, o);
    }
    // all lanes hold the winner after the butterfly
    const int k = (int)(best & (u64)(NCODES - 1));
    if (lane == 0) idx_f[row] = (float)k;

    // ---- fused gather + ST + loss (bit-identical arithmetic) ----
    const float4 e  = *(const float4*)(cb + (size_t)k * DIM + lane * 4);
    const float4 zv = *(const float4*)&zrow_s[w][lane * 4];
    const float dx = e.x - zv.x, dy = e.y - zv.y, dz = e.z - zv.z, dw = e.w - zv.w;
    float4 o;
    o.x = zv.x + dx; o.y = zv.y + dy; o.z = zv.z + dz; o.w = zv.w + dw;
    *(float4*)(zq_out + (size_t)row * DIM + lane * 4) = o;   // overwrites this row's mask (done with it)
    float s = dx * dx + dy * dy + dz * dz + dw * dw;
    #pragma unroll
    for (int off = 32; off > 0; off >>= 1) s += __shfl_down(s, off, 64);
    if (lane == 0) wsum[w] = s;
    __syncthreads();
    if (threadIdx.x == 0)
        atomicAdd(loss_acc, wsum[0] + wsum[1] + wsum[2] + wsum[3]);
}

// ============================================================================
// Kernel E: finalize scalars.
// ============================================================================
__global__ void vq_finalize_kernel(const float* __restrict__ loss_acc,
                                   float* __restrict__ out_losses) {
    const float mean = *loss_acc * (1.0f / (float)(BATCH * DIM));  // /2^23 exact
    out_losses[0] = mean + BETA * mean;    // vq_loss
    out_losses[1] = mean;                  // cb_loss
    out_losses[2] = mean;                  // commit_loss
}

// ============================================================================
extern "C" void kernel_launch(void* const* d_in, const int* in_sizes, int n_in,
                              void* d_out, int out_size, void* d_ws, size_t ws_size,
                              hipStream_t stream) {
    const float* z  = (const float*)d_in[0];   // [32768, 256] fp32
    const float* cb = (const float*)d_in[1];   // [8192, 256]  fp32

    float* out    = (float*)d_out;
    float* zq     = out;                                   // [32768*256]
    float* idx_f  = out + (size_t)BATCH * DIM;             // [32768]
    float* losses = out + (size_t)BATCH * DIM + BATCH;     // [3]
    uchar_t* mask = (uchar_t*)d_out;                       // zq region reused: 1 KB/row

    // ws layout (~20.5 MB): ctrl[256 f] | e2 | z2 | tilemin(u16) | zh(u16) | eh(u16)
    float*    ws        = (float*)d_ws;
    float*    loss_acc  = ws;                                       // [0]
    float*    e2        = ws + 256;                                 // 8192 f
    float*    z2        = e2 + NCODES;                              // 32768 f
    ushort_t* tilemin   = (ushort_t*)(z2 + BATCH);                  // 32768*64 u16
    ushort_t* zh        = tilemin + (size_t)BATCH * 64;             // 32768*256 u16
    ushort_t* eh        = zh + (size_t)BATCH * DIM;                 // 8192*256 u16

    vq_prep_kernel<<<(NCODES + BATCH) / 4, 256, 0, stream>>>(z, cb, e2, z2, eh, zh, loss_acc);
    vq_screen_kernel<<<(BATCH / 128) * (NCODES / 128), 256, 0, stream>>>(zh, eh, e2, tilemin, mask);
    vq_select_kernel<<<BATCH / 4, 256, 0, stream>>>(z, cb, e2, z2, tilemin, mask, idx_f, zq, loss_acc);
    vq_finalize_kernel<<<1, 1, 0, stream>>>(loss_acc, losses);
}